// Round 22
// baseline (86.471 us; speedup 1.0000x reference)
//
#include <hip/hip_runtime.h>

#define Bsz 4
#define Cch 64
#define Hh 128
#define Ww 128
#define NOFF 18      // 2*3*3 offset channels
#define CK 576       // 64*9 reduction length for deform einsum (K = k*64 + c)
#define SMPB 1152    // smp row stride in BYTES (576 bf16, XOR-swizzled)

typedef __attribute__((ext_vector_type(8))) short short8;
typedef __attribute__((ext_vector_type(4))) float floatx4;
typedef __fp16 half2v __attribute__((ext_vector_type(2)));

__device__ __forceinline__ unsigned short f2bf(float f) {
    union { float f; unsigned u; } v; v.f = f;
    unsigned r = v.u + 0x7fff + ((v.u >> 16) & 1);   // round-to-nearest-even
    return (unsigned short)(r >> 16);
}
__device__ __forceinline__ float bflo(unsigned d) {
    union { unsigned u; float f; } v; v.u = d << 16; return v.f;
}
__device__ __forceinline__ float bfhi(unsigned d) {
    union { unsigned u; float f; } v; v.u = d & 0xffff0000u; return v.f;
}
__device__ __forceinline__ unsigned cvtpk(float lo, float hi) {   // {bf16(lo), bf16(hi)<<16}
    unsigned r;
    asm("v_cvt_pk_bf16_f32 %0, %1, %2" : "=v"(r) : "v"(lo), "v"(hi));
    return r;
}
__device__ __forceinline__ unsigned h2bits(half2v h) {
    union { half2v h; unsigned u; } v; v.h = h; return v.u;
}
__device__ __forceinline__ half2v bits2h(unsigned u) {
    union { half2v h; unsigned u; } v; v.u = u; return v.h;
}
// Batched gather load: asm so the compiler cannot fuse it with consumers.
// A batch MUST be drained with asm vmcnt + sched_barrier before use.
__device__ __forceinline__ uint4 gld4(const void* p) {
    uint4 q;
    asm volatile("global_load_dwordx4 %0, %1, off" : "=v"(q) : "v"(p) : "memory");
    return q;
}
// Swizzled smp addressing: row stride 1152B, byte-in-row XOR'd by (row&7)<<4.
// Write granule 8B, read granule 16B -- XOR bits 4..6 preserve both.
__device__ __forceinline__ char* smpp(char* base, int row, int bir) {
    return base + row * SMPB + (bir ^ ((row & 7) << 4));
}

// ---------------------------------------------------------------------------
// Prep kernel.
//   blocks 0..511  : build xpair[b][h*w][128ch] u32 = {bf16 v(pos,c), bf16 v(pos+1,c)}
//   blocks 512..655: deform weight w[oc][c][tap] -> wbf[oc][tap*64+c] bf16
//   blocks 656..799: offset weight wo[oc][ci][tap] -> w9[tap][32ocp][128ci] bf16
__global__ __launch_bounds__(256) void prep(const float* __restrict__ x,
                                            const float* __restrict__ ref,
                                            const float* __restrict__ wo,
                                            const float* __restrict__ w,
                                            unsigned* __restrict__ xpair,
                                            unsigned short* __restrict__ w9,
                                            unsigned short* __restrict__ wbf) {
    __shared__ unsigned tile[64][130];   // [cpair][px]; stride 130 u32
    int bid = blockIdx.x;
    int tid = threadIdx.x;
    if (bid < 512) {
        int b = bid >> 7;
        int h = bid & 127;
        int px2 = tid & 63;              // pixel pair: px = 2*px2, 2*px2+1
        int cg = tid >> 6;               // 32-channel group
        const float* xb = x + ((size_t)b << 20) + (h << 7) + (px2 << 1);
        const float* rb = ref + ((size_t)b << 20) + (h << 7) + (px2 << 1);
#pragma unroll
        for (int j = 0; j < 16; ++j) {
            int c0 = cg * 32 + 2 * j;
            const float* s = (c0 < 64) ? xb : rb;
            int cl = c0 & 63;
            float2 va = *(const float2*)(s + ((size_t)cl << 14));
            float2 vb = *(const float2*)(s + ((size_t)(cl + 1) << 14));
            unsigned w0 = (unsigned)f2bf(va.x) | ((unsigned)f2bf(vb.x) << 16);
            unsigned w1 = (unsigned)f2bf(va.y) | ((unsigned)f2bf(vb.y) << 16);
            *(uint2*)(&tile[c0 >> 1][px2 << 1]) = make_uint2(w0, w1);
        }
        __syncthreads();
#pragma unroll
        for (int it = 0; it < 16; ++it) {
            int idx = it * 256 + tid;
            int cq5 = idx & 31;          // 4-channel group
            int pos = idx >> 5;          // 0..127
            int posn = min(pos + 1, 127);
            unsigned t0 = tile[2 * cq5][pos], t0n = tile[2 * cq5][posn];
            unsigned t1 = tile[2 * cq5 + 1][pos], t1n = tile[2 * cq5 + 1][posn];
            uint4 o;
            o.x = (t0 & 0xffffu) | (t0n << 16);
            o.y = (t0 >> 16) | (t0n & 0xffff0000u);
            o.z = (t1 & 0xffffu) | (t1n << 16);
            o.w = (t1 >> 16) | (t1n & 0xffff0000u);
            *(uint4*)(xpair + (((size_t)(b << 14) + (h << 7) + pos) << 7) + (cq5 << 2)) = o;
        }
    } else if (bid < 656) {
        int t = (bid - 512) * 256 + tid;
        if (t < Cch * CK) {
            int oc = t / CK;
            int rem = t % CK;
            int k = rem >> 6, c = rem & 63;
            wbf[t] = f2bf(w[(oc * Cch + c) * 9 + k]);
        }
    } else {
        int t = (bid - 656) * 256 + tid;
        if (t < 9 * 32 * 128) {
            int ci = t & 127, ocp = (t >> 7) & 31, tap = t >> 12;
            w9[t] = (ocp < NOFF) ? f2bf(wo[(ocp * 128 + ci) * 9 + tap]) : (unsigned short)0;
        }
    }
}

// ---------------------------------------------------------------------------
// Fused kernel, 32-px blocks, LDS ~30.2 KB -> 5 blocks/CU.
// A0 : 13 asm-batched loads -> vmcnt(0) -> 13 LDS writes (1 round-trip).
// A1 : offset MFMA; wave (to,kh) runs BOTH sub-strips reusing w9 fragments.
// FIN: kh==0 waves finalize offsets; packed-f16 corner weights + meta written
//      into tile3's dead space (union B region).
// B/B1 SEQUENTIAL per strip: 18 asm-batched gathers -> packs -> barrier ->
//      deform MFMA -> store; strip-1 reuses smp (wtsH/metaB live at offsets
//      smp never touches -> no snapshot needed).
__global__ __launch_bounds__(256, 5) void fused_align(
        const unsigned* __restrict__ xpair,
        const unsigned short* __restrict__ w9,
        const unsigned short* __restrict__ wbf,
        const float* __restrict__ bias,
        float* __restrict__ out) {
    __shared__ union {
        struct {
            unsigned short tile3[3 * 34 * 128];   // 26112 B (offsets 0..26112)
            float red[2][2][64][4];               // 4096 B  (26112..30208)
        } A;
        struct {
            uint2 wtsH[288];                      // 2304 B  (0..2304)
            int2 metaB[288];                      // 2304 B  (2304..4608)
            unsigned short smp[16][576];          // 18432 B (4608..23040)
        } B;                                      // all inside tile3's space
    } u;

    int bi0 = blockIdx.x;
    int bi = ((bi0 & 7) << 8) | (bi0 >> 3);   // XCD swizzle (2048 = 8*256)
    int b = bi >> 9;
    int rem = bi & 511;
    int h = rem >> 2;
    int w0 = (rem & 3) << 5;
    int tid = threadIdx.x;
    int wv = tid >> 6, lane = tid & 63;
    int to = wv & 1;          // oc tile (offset conv)
    int kh = wv >> 1;         // ci half (0: x, 1: ref)
    int r16 = lane & 15;
    int g = lane >> 4;

    const unsigned* xp32 = xpair + ((size_t)b << 21);   // b * 16384 pos * 128 u32

    float bias4[4] = {0.f, 0.f, 0.f, 0.f};
    if (kh == 0) {
#pragma unroll
        for (int r = 0; r < 4; ++r) {
            int oc = to * 16 + g * 4 + r;
            if (oc < NOFF) bias4[r] = bias[oc];
        }
    }

    // ---- Phase A0: 13 asm loads in flight -> vmcnt(0) -> LDS writes ----
    {
        uint4 qa[13];
        bool val[13];
#pragma unroll
        for (int it = 0; it < 13; ++it) {
            int idx = it * 256 + tid;
            int idc = (idx < 3264) ? idx : 0;
            int cq4 = idc & 31;              // 4-channel group
            int pos = idc >> 5;              // row*34 + xx
            int row = pos / 34, xx = pos % 34;
            int yy = h + row - 1, xg = w0 + xx - 1;
            bool v = ((unsigned)yy < (unsigned)Hh) && ((unsigned)xg < (unsigned)Ww);
            val[it] = v;
            const unsigned* ap = xp32 + (((yy << 7) + xg) << 7) + (cq4 << 2);
            qa[it] = gld4(v ? (const void*)ap : (const void*)xp32);
        }
        asm volatile("s_waitcnt vmcnt(0)" ::: "memory");
        __builtin_amdgcn_sched_barrier(0);
#pragma unroll
        for (int it = 0; it < 13; ++it) {
            int idx = it * 256 + tid;
            if (idx < 3264) {
                int cq4 = idx & 31;
                int pos = idx >> 5;
                int xx = pos % 34;
                uint4 q = val[it] ? qa[it] : make_uint4(0u, 0u, 0u, 0u);
                unsigned p0v = (q.x & 0xffffu) | (q.y << 16);
                unsigned p1v = (q.z & 0xffffu) | (q.w << 16);
                int ci0 = cq4 << 2;
                *(uint2*)(&u.A.tile3[(pos << 7) + (ci0 ^ ((xx & 7) << 3))]) =
                    make_uint2(p0v, p1v);
            }
        }
    }
    __syncthreads();

    // ---- Phase A1: offset conv MFMA; both strips share w9 fragments ----
    floatx4 accA0 = {0.f, 0.f, 0.f, 0.f};
    floatx4 accA1 = {0.f, 0.f, 0.f, 0.f};
#pragma unroll
    for (int tap = 0; tap < 9; ++tap) {
        int dy = tap / 3, dx = tap % 3;
        const unsigned short* arow = w9 + ((size_t)(tap * 32 + to * 16 + r16) << 7) + kh * 64;
        short8 a0 = *(const short8*)(arow + g * 8);          // k-group g, kk=0
        short8 a1 = *(const short8*)(arow + 32 + g * 8);     // k-group g, kk=1
#pragma unroll
        for (int s = 0; s < 2; ++s) {
            int xxr = r16 + dx + s * 16;                     // 0..33
            const unsigned short* brow = &u.A.tile3[(dy * 34 + xxr) << 7];
            int sw = (xxr & 7) << 3;
            int cb0 = kh * 64 + g * 8;
            short8 bb0 = *(const short8*)(brow + (cb0 ^ sw));
            short8 bb1 = *(const short8*)(brow + ((cb0 + 32) ^ sw));
            if (s == 0) {
                accA0 = __builtin_amdgcn_mfma_f32_16x16x32_bf16(a0, bb0, accA0, 0, 0, 0);
                accA0 = __builtin_amdgcn_mfma_f32_16x16x32_bf16(a1, bb1, accA0, 0, 0, 0);
            } else {
                accA1 = __builtin_amdgcn_mfma_f32_16x16x32_bf16(a0, bb0, accA1, 0, 0, 0);
                accA1 = __builtin_amdgcn_mfma_f32_16x16x32_bf16(a1, bb1, accA1, 0, 0, 0);
            }
        }
    }
    if (kh == 1) {
#pragma unroll
        for (int r = 0; r < 4; ++r) { u.A.red[0][to][lane][r] = accA0[r]; u.A.red[1][to][lane][r] = accA1[r]; }
    }
    __syncthreads();

    // ---- FIN: offsets -> packed-f16 corner weights + row offsets ----
    // Writes u.B.wtsH/metaB (tile3 dead); reads u.A.red (disjoint bytes).
    if (kh == 0 && (to == 0 || g == 0)) {
        int ntap = (to == 0) ? 2 : 1;
        int kbase = (to * 16 + g * 4) >> 1;
#pragma unroll
        for (int s = 0; s < 2; ++s) {
            float vout[4];
#pragma unroll
            for (int r = 0; r < 4; ++r) {
                float v = (s == 0 ? accA0[r] : accA1[r]) + u.A.red[s][to][lane][r] + bias4[r];
                vout[r] = fminf(fmaxf(v, -10.0f), 10.0f);
            }
            int p = s * 16 + r16;
#pragma unroll
            for (int t = 0; t < 2; ++t) {
                if (t < ntap) {
                    int k = kbase + t;
                    float dyo = vout[2 * t], dxo = vout[2 * t + 1];
                    int ky = k / 3, kx = k % 3;
                    float ys = (float)(h - 1 + ky) + dyo;
                    float xs = (float)(w0 + p - 1 + kx) + dxo;
                    float fy = floorf(ys), fx = floorf(xs);
                    int iy0 = (int)fy, ix0 = (int)fx;
                    float ty = ys - fy, tx = xs - fx;
                    float wy0 = (1.f - ty) * (((unsigned)iy0 < (unsigned)Hh) ? 1.f : 0.f);
                    float wy1 = ty         * (((unsigned)(iy0 + 1) < (unsigned)Hh) ? 1.f : 0.f);
                    float wx0 = (1.f - tx) * (((unsigned)ix0 < (unsigned)Ww) ? 1.f : 0.f);
                    float wx1 = tx         * (((unsigned)(ix0 + 1) < (unsigned)Ww) ? 1.f : 0.f);
                    int ixb  = min(max(ix0, 0), Ww - 2);
                    int iy0c = min(max(iy0, 0), Hh - 1);
                    int iy1c = min(max(iy0 + 1, 0), Hh - 1);
                    bool s0v = (min(max(ix0, 0), Ww - 1) != ixb);
                    bool s1v = (min(max(ix0 + 1, 0), Ww - 1) != ixb);
                    float w00 = wy0 * wx0, w01 = wy0 * wx1, w10 = wy1 * wx0, w11 = wy1 * wx1;
                    float A  = (s0v ? 0.f : w00) + (s1v ? 0.f : w01);   // (y0, ixb)
                    float Bw = (s0v ? w00 : 0.f) + (s1v ? w01 : 0.f);   // (y0, ixb+1)
                    float Cw = (s0v ? 0.f : w10) + (s1v ? 0.f : w11);   // (y1, ixb)
                    float Dw = (s0v ? w10 : 0.f) + (s1v ? w11 : 0.f);   // (y1, ixb+1)
                    u.B.wtsH[p * 9 + k] = make_uint2(
                        h2bits(__builtin_amdgcn_cvt_pkrtz(A, Bw)),
                        h2bits(__builtin_amdgcn_cvt_pkrtz(Cw, Dw)));
                    u.B.metaB[p * 9 + k] = make_int2(((iy0c << 7) + ixb) << 9,
                                                     ((iy1c << 7) + ixb) << 9);
                }
            }
        }
    }
    __syncthreads();   // wtsH/metaB ready

    // ---- Phase B/B1: sequential per strip; smp never clobbers wtsH/metaB ----
    {
        int p0 = tid >> 4, cq = tid & 15;
        const char* xbB = (const char*)xpair + ((size_t)b << 23) + cq * 16;
        char* smpBase = (char*)u.B.smp;
        size_t obase = ((size_t)(b * Cch + wv * 16 + g * 4)) << 14;
        int hwb = (h << 7) + w0 + r16;

#pragma unroll
        for (int s = 0; s < 2; ++s) {
            int p = p0 + s * 16;
            // gather: 18 asm loads in flight -> drain -> pack into smp rows 0..15
            {
                uint4 q0[9], q1[9];
#pragma unroll
                for (int k = 0; k < 9; ++k) {
                    int2 mm = u.B.metaB[p * 9 + k];
                    q0[k] = gld4(xbB + mm.x);
                    q1[k] = gld4(xbB + mm.y);
                }
                asm volatile("s_waitcnt vmcnt(0)" ::: "memory");
                __builtin_amdgcn_sched_barrier(0);
#pragma unroll
                for (int k = 0; k < 9; ++k) {
                    uint2 wh = u.B.wtsH[p * 9 + k];
                    half2v hAB = bits2h(wh.x), hCD = bits2h(wh.y);
                    float wAv = (float)hAB.x, wBv = (float)hAB.y;
                    float wCv = (float)hCD.x, wDv = (float)hCD.y;
                    uint4 qa = q0[k], qb = q1[k];
                    float s0 = bflo(qa.x)*wAv + bfhi(qa.x)*wBv + bflo(qb.x)*wCv + bfhi(qb.x)*wDv;
                    float s1 = bflo(qa.y)*wAv + bfhi(qa.y)*wBv + bflo(qb.y)*wCv + bfhi(qb.y)*wDv;
                    float s2 = bflo(qa.z)*wAv + bfhi(qa.z)*wBv + bflo(qb.z)*wCv + bfhi(qb.z)*wDv;
                    float s3 = bflo(qa.w)*wAv + bfhi(qa.w)*wBv + bflo(qb.w)*wCv + bfhi(qb.w)*wDv;
                    *(uint2*)smpp(smpBase, p0, k * 128 + cq * 8) =
                        make_uint2(cvtpk(s0, s1), cvtpk(s2, s3));
                }
            }
            __syncthreads();   // smp ready for this strip

            // deform MFMA for this strip
            {
                floatx4 acc = {0.f, 0.f, 0.f, 0.f};
                const short8* ap = (const short8*)(wbf + (size_t)(wv * 16 + r16) * CK + g * 8);
#pragma unroll
                for (int kk = 0; kk < 18; ++kk) {
                    short8 a = ap[kk * 4];
                    short8 v0 = *(const short8*)smpp(smpBase, r16, g * 16 + kk * 64);
                    acc = __builtin_amdgcn_mfma_f32_16x16x32_bf16(a, v0, acc, 0, 0, 0);
                }
                int hw = hwb + s * 16;
#pragma unroll
                for (int r = 0; r < 4; ++r)
                    out[obase + ((size_t)r << 14) + hw] = acc[r];
            }
            if (s == 0) __syncthreads();   // smp reads done before strip-1 overwrites
        }
    }
}

// ---------------------------------------------------------------------------
extern "C" void kernel_launch(void* const* d_in, const int* in_sizes, int n_in,
                              void* d_out, int out_size, void* d_ws, size_t ws_size,
                              hipStream_t stream) {
    const float* x      = (const float*)d_in[0];
    const float* ref    = (const float*)d_in[1];
    const float* wo     = (const float*)d_in[2];
    const float* bias   = (const float*)d_in[3];
    const float* weight = (const float*)d_in[4];
    float* out = (float*)d_out;

    unsigned short* w9  = (unsigned short*)d_ws;                      // 72 KB
    unsigned short* wbf = (unsigned short*)((char*)d_ws + 262144);    // 72 KB
    unsigned* xpair     = (unsigned*)((char*)d_ws + 524288);          // 33.5 MB

    hipLaunchKernelGGL(prep, dim3(800), dim3(256), 0, stream,
                       x, ref, wo, weight, xpair, w9, wbf);
    hipLaunchKernelGGL(fused_align, dim3(2048), dim3(256), 0, stream,
                       xpair, w9, wbf, bias, out);
}

// Round 23
// 66.562 us; speedup vs baseline: 1.2991x; 1.2991x over previous
//
#include <hip/hip_runtime.h>

#define Bsz 4
#define Cch 64
#define Hh 128
#define Ww 128
#define NOFF 18      // 2*3*3 offset channels
#define CK 576       // 64*9 reduction length for deform einsum (K = k*64 + c)
#define SMPB 1152    // smp row stride in BYTES (576 bf16, XOR-swizzled)

typedef __attribute__((ext_vector_type(8))) short short8;
typedef __attribute__((ext_vector_type(4))) float floatx4;
typedef __fp16 half2v __attribute__((ext_vector_type(2)));

__device__ __forceinline__ unsigned short f2bf(float f) {
    union { float f; unsigned u; } v; v.f = f;
    unsigned r = v.u + 0x7fff + ((v.u >> 16) & 1);   // round-to-nearest-even
    return (unsigned short)(r >> 16);
}
__device__ __forceinline__ float bflo(unsigned d) {
    union { unsigned u; float f; } v; v.u = d << 16; return v.f;
}
__device__ __forceinline__ float bfhi(unsigned d) {
    union { unsigned u; float f; } v; v.u = d & 0xffff0000u; return v.f;
}
__device__ __forceinline__ unsigned cvtpk(float lo, float hi) {   // {bf16(lo), bf16(hi)<<16}
    unsigned r;
    asm("v_cvt_pk_bf16_f32 %0, %1, %2" : "=v"(r) : "v"(lo), "v"(hi));
    return r;
}
__device__ __forceinline__ unsigned h2bits(half2v h) {
    union { half2v h; unsigned u; } v; v.h = h; return v.u;
}
__device__ __forceinline__ half2v bits2h(unsigned u) {
    union { half2v h; unsigned u; } v; v.u = u; return v.h;
}
// Batched gather load: asm so the compiler cannot fuse it with consumers.
// A batch MUST be drained with asm vmcnt + sched_barrier before use.
__device__ __forceinline__ uint4 gld4(const void* p) {
    uint4 q;
    asm volatile("global_load_dwordx4 %0, %1, off" : "=v"(q) : "v"(p) : "memory");
    return q;
}
// Swizzled smp addressing: row stride 1152B, byte-in-row XOR'd by (row&7)<<4.
// Write granule 8B, read granule 16B -- XOR bits 4..6 preserve both.
__device__ __forceinline__ char* smpp(char* base, int row, int bir) {
    return base + row * SMPB + (bir ^ ((row & 7) << 4));
}

// ---------------------------------------------------------------------------
// Prep kernel.
//   blocks 0..511  : build xpair[b][h*w][128ch] u32 = {bf16 v(pos,c), bf16 v(pos+1,c)}
//   blocks 512..655: deform weight w[oc][c][tap] -> wbf[oc][tap*64+c] bf16
//   blocks 656..799: offset weight wo[oc][ci][tap] -> w9[tap][32ocp][128ci] bf16
__global__ __launch_bounds__(256) void prep(const float* __restrict__ x,
                                            const float* __restrict__ ref,
                                            const float* __restrict__ wo,
                                            const float* __restrict__ w,
                                            unsigned* __restrict__ xpair,
                                            unsigned short* __restrict__ w9,
                                            unsigned short* __restrict__ wbf) {
    __shared__ unsigned tile[64][130];   // [cpair][px]; stride 130 u32
    int bid = blockIdx.x;
    int tid = threadIdx.x;
    if (bid < 512) {
        int b = bid >> 7;
        int h = bid & 127;
        int px2 = tid & 63;              // pixel pair: px = 2*px2, 2*px2+1
        int cg = tid >> 6;               // 32-channel group
        const float* xb = x + ((size_t)b << 20) + (h << 7) + (px2 << 1);
        const float* rb = ref + ((size_t)b << 20) + (h << 7) + (px2 << 1);
#pragma unroll
        for (int j = 0; j < 16; ++j) {
            int c0 = cg * 32 + 2 * j;
            const float* s = (c0 < 64) ? xb : rb;
            int cl = c0 & 63;
            float2 va = *(const float2*)(s + ((size_t)cl << 14));
            float2 vb = *(const float2*)(s + ((size_t)(cl + 1) << 14));
            unsigned w0 = (unsigned)f2bf(va.x) | ((unsigned)f2bf(vb.x) << 16);
            unsigned w1 = (unsigned)f2bf(va.y) | ((unsigned)f2bf(vb.y) << 16);
            *(uint2*)(&tile[c0 >> 1][px2 << 1]) = make_uint2(w0, w1);
        }
        __syncthreads();
#pragma unroll
        for (int it = 0; it < 16; ++it) {
            int idx = it * 256 + tid;
            int cq5 = idx & 31;          // 4-channel group
            int pos = idx >> 5;          // 0..127
            int posn = min(pos + 1, 127);
            unsigned t0 = tile[2 * cq5][pos], t0n = tile[2 * cq5][posn];
            unsigned t1 = tile[2 * cq5 + 1][pos], t1n = tile[2 * cq5 + 1][posn];
            uint4 o;
            o.x = (t0 & 0xffffu) | (t0n << 16);
            o.y = (t0 >> 16) | (t0n & 0xffff0000u);
            o.z = (t1 & 0xffffu) | (t1n << 16);
            o.w = (t1 >> 16) | (t1n & 0xffff0000u);
            *(uint4*)(xpair + (((size_t)(b << 14) + (h << 7) + pos) << 7) + (cq5 << 2)) = o;
        }
    } else if (bid < 656) {
        int t = (bid - 512) * 256 + tid;
        if (t < Cch * CK) {
            int oc = t / CK;
            int rem = t % CK;
            int k = rem >> 6, c = rem & 63;
            wbf[t] = f2bf(w[(oc * Cch + c) * 9 + k]);
        }
    } else {
        int t = (bid - 656) * 256 + tid;
        if (t < 9 * 32 * 128) {
            int ci = t & 127, ocp = (t >> 7) & 31, tap = t >> 12;
            w9[t] = (ocp < NOFF) ? f2bf(wo[(ocp * 128 + ci) * 9 + tap]) : (unsigned short)0;
        }
    }
}

// ---------------------------------------------------------------------------
// Fused kernel, 32-px blocks, LDS squeezed to 36864B -> 4 blocks/CU.
// A0 : 13 asm-batched loads -> vmcnt(0) -> 13 LDS writes (1 round-trip).
// A1 : offset MFMA; wave (to,kh) runs BOTH sub-strips reusing w9 fragments.
// FIN: kh==0 waves finalize offsets; corner weights packed f16 + meta into
//      the union tail (tile3/red dead).
// B  : strip-0 reads wts/meta from LDS (its smp writes don't clobber them);
//      strip-1 snapshots its 9 wts+meta to regs behind barriers, since its
//      smp rows 16..31 overwrite the union tail.
// B1 : deform MFMA; both sub-strips reuse wbf fragments; swizzled smp reads.
__global__ __launch_bounds__(256, 4) void fused_align(
        const unsigned* __restrict__ xpair,
        const unsigned short* __restrict__ w9,
        const unsigned short* __restrict__ wbf,
        const float* __restrict__ bias,
        float* __restrict__ out) {
    __shared__ union {
        struct {
            unsigned short tile3[3 * 34 * 128];   // 26112 B
            float red[2][2][64][4];               // 4096 B  [strip][to]
            uint2 wtsH[288];                      // 2304 B  packed f16 {A,B},{C,D}
            int2 metaB[288];                      // 2304 B  row byte offsets
        } A;                                      // 34816 B
        unsigned short smp[32][576];              // 36864 B (XOR-swizzled rows)
    } u;

    int bi0 = blockIdx.x;
    int bi = ((bi0 & 7) << 8) | (bi0 >> 3);   // XCD swizzle (2048 = 8*256)
    int b = bi >> 9;
    int rem = bi & 511;
    int h = rem >> 2;
    int w0 = (rem & 3) << 5;
    int tid = threadIdx.x;
    int wv = tid >> 6, lane = tid & 63;
    int to = wv & 1;          // oc tile (offset conv)
    int kh = wv >> 1;         // ci half (0: x, 1: ref)
    int r16 = lane & 15;
    int g = lane >> 4;

    const unsigned* xp32 = xpair + ((size_t)b << 21);   // b * 16384 pos * 128 u32

    float bias4[4] = {0.f, 0.f, 0.f, 0.f};
    if (kh == 0) {
#pragma unroll
        for (int r = 0; r < 4; ++r) {
            int oc = to * 16 + g * 4 + r;
            if (oc < NOFF) bias4[r] = bias[oc];
        }
    }

    // ---- Phase A0: 13 asm loads in flight -> vmcnt(0) -> LDS writes ----
    {
        uint4 qa[13];
        bool val[13];
#pragma unroll
        for (int it = 0; it < 13; ++it) {
            int idx = it * 256 + tid;
            int idc = (idx < 3264) ? idx : 0;
            int cq4 = idc & 31;              // 4-channel group
            int pos = idc >> 5;              // row*34 + xx
            int row = pos / 34, xx = pos % 34;
            int yy = h + row - 1, xg = w0 + xx - 1;
            bool v = ((unsigned)yy < (unsigned)Hh) && ((unsigned)xg < (unsigned)Ww);
            val[it] = v;
            const unsigned* ap = xp32 + (((yy << 7) + xg) << 7) + (cq4 << 2);
            qa[it] = gld4(v ? (const void*)ap : (const void*)xp32);
        }
        asm volatile("s_waitcnt vmcnt(0)" ::: "memory");
        __builtin_amdgcn_sched_barrier(0);
#pragma unroll
        for (int it = 0; it < 13; ++it) {
            int idx = it * 256 + tid;
            if (idx < 3264) {
                int cq4 = idx & 31;
                int pos = idx >> 5;
                int xx = pos % 34;
                uint4 q = val[it] ? qa[it] : make_uint4(0u, 0u, 0u, 0u);
                unsigned p0v = (q.x & 0xffffu) | (q.y << 16);
                unsigned p1v = (q.z & 0xffffu) | (q.w << 16);
                int ci0 = cq4 << 2;
                *(uint2*)(&u.A.tile3[(pos << 7) + (ci0 ^ ((xx & 7) << 3))]) =
                    make_uint2(p0v, p1v);
            }
        }
    }
    __syncthreads();

    // ---- Phase A1: offset conv MFMA; both strips share w9 fragments ----
    floatx4 accA0 = {0.f, 0.f, 0.f, 0.f};
    floatx4 accA1 = {0.f, 0.f, 0.f, 0.f};
#pragma unroll
    for (int tap = 0; tap < 9; ++tap) {
        int dy = tap / 3, dx = tap % 3;
        const unsigned short* arow = w9 + ((size_t)(tap * 32 + to * 16 + r16) << 7) + kh * 64;
        short8 a0 = *(const short8*)(arow + g * 8);          // k-group g, kk=0
        short8 a1 = *(const short8*)(arow + 32 + g * 8);     // k-group g, kk=1
#pragma unroll
        for (int s = 0; s < 2; ++s) {
            int xxr = r16 + dx + s * 16;                     // 0..33
            const unsigned short* brow = &u.A.tile3[(dy * 34 + xxr) << 7];
            int sw = (xxr & 7) << 3;
            int cb0 = kh * 64 + g * 8;
            short8 bb0 = *(const short8*)(brow + (cb0 ^ sw));
            short8 bb1 = *(const short8*)(brow + ((cb0 + 32) ^ sw));
            if (s == 0) {
                accA0 = __builtin_amdgcn_mfma_f32_16x16x32_bf16(a0, bb0, accA0, 0, 0, 0);
                accA0 = __builtin_amdgcn_mfma_f32_16x16x32_bf16(a1, bb1, accA0, 0, 0, 0);
            } else {
                accA1 = __builtin_amdgcn_mfma_f32_16x16x32_bf16(a0, bb0, accA1, 0, 0, 0);
                accA1 = __builtin_amdgcn_mfma_f32_16x16x32_bf16(a1, bb1, accA1, 0, 0, 0);
            }
        }
    }
    if (kh == 1) {
#pragma unroll
        for (int r = 0; r < 4; ++r) { u.A.red[0][to][lane][r] = accA0[r]; u.A.red[1][to][lane][r] = accA1[r]; }
    }
    __syncthreads();

    // ---- FIN: offsets -> packed-f16 corner weights + row offsets ----
    if (kh == 0 && (to == 0 || g == 0)) {
        int ntap = (to == 0) ? 2 : 1;
        int kbase = (to * 16 + g * 4) >> 1;
#pragma unroll
        for (int s = 0; s < 2; ++s) {
            float vout[4];
#pragma unroll
            for (int r = 0; r < 4; ++r) {
                float v = (s == 0 ? accA0[r] : accA1[r]) + u.A.red[s][to][lane][r] + bias4[r];
                vout[r] = fminf(fmaxf(v, -10.0f), 10.0f);
            }
            int p = s * 16 + r16;
#pragma unroll
            for (int t = 0; t < 2; ++t) {
                if (t < ntap) {
                    int k = kbase + t;
                    float dyo = vout[2 * t], dxo = vout[2 * t + 1];
                    int ky = k / 3, kx = k % 3;
                    float ys = (float)(h - 1 + ky) + dyo;
                    float xs = (float)(w0 + p - 1 + kx) + dxo;
                    float fy = floorf(ys), fx = floorf(xs);
                    int iy0 = (int)fy, ix0 = (int)fx;
                    float ty = ys - fy, tx = xs - fx;
                    float wy0 = (1.f - ty) * (((unsigned)iy0 < (unsigned)Hh) ? 1.f : 0.f);
                    float wy1 = ty         * (((unsigned)(iy0 + 1) < (unsigned)Hh) ? 1.f : 0.f);
                    float wx0 = (1.f - tx) * (((unsigned)ix0 < (unsigned)Ww) ? 1.f : 0.f);
                    float wx1 = tx         * (((unsigned)(ix0 + 1) < (unsigned)Ww) ? 1.f : 0.f);
                    int ixb  = min(max(ix0, 0), Ww - 2);
                    int iy0c = min(max(iy0, 0), Hh - 1);
                    int iy1c = min(max(iy0 + 1, 0), Hh - 1);
                    bool s0v = (min(max(ix0, 0), Ww - 1) != ixb);
                    bool s1v = (min(max(ix0 + 1, 0), Ww - 1) != ixb);
                    float w00 = wy0 * wx0, w01 = wy0 * wx1, w10 = wy1 * wx0, w11 = wy1 * wx1;
                    float A  = (s0v ? 0.f : w00) + (s1v ? 0.f : w01);   // (y0, ixb)
                    float Bw = (s0v ? w00 : 0.f) + (s1v ? w01 : 0.f);   // (y0, ixb+1)
                    float Cw = (s0v ? 0.f : w10) + (s1v ? 0.f : w11);   // (y1, ixb)
                    float Dw = (s0v ? w10 : 0.f) + (s1v ? w11 : 0.f);   // (y1, ixb+1)
                    u.A.wtsH[p * 9 + k] = make_uint2(
                        h2bits(__builtin_amdgcn_cvt_pkrtz(A, Bw)),
                        h2bits(__builtin_amdgcn_cvt_pkrtz(Cw, Dw)));
                    u.A.metaB[p * 9 + k] = make_int2(((iy0c << 7) + ixb) << 9,
                                                     ((iy1c << 7) + ixb) << 9);
                }
            }
        }
    }
    __syncthreads();   // wtsH/metaB ready; tile3/red dead

    // ---- Phase B ----
    {
        int p0 = tid >> 4, cq = tid & 15;
        const char* xbB = (const char*)xpair + ((size_t)b << 23) + cq * 16;
        char* smpBase = (char*)u.smp;

#define PACK1(p, qa, qb, whx, why)                                                    \
        {                                                                             \
            half2v hAB = bits2h(whx), hCD = bits2h(why);                              \
            float wAv = (float)hAB.x, wBv = (float)hAB.y;                             \
            float wCv = (float)hCD.x, wDv = (float)hCD.y;                             \
            float s0 = bflo(qa.x)*wAv + bfhi(qa.x)*wBv + bflo(qb.x)*wCv + bfhi(qb.x)*wDv; \
            float s1 = bflo(qa.y)*wAv + bfhi(qa.y)*wBv + bflo(qb.y)*wCv + bfhi(qb.y)*wDv; \
            float s2 = bflo(qa.z)*wAv + bfhi(qa.z)*wBv + bflo(qb.z)*wCv + bfhi(qb.z)*wDv; \
            float s3 = bflo(qa.w)*wAv + bfhi(qa.w)*wBv + bflo(qb.w)*wCv + bfhi(qb.w)*wDv; \
            *(uint2*)smpp(smpBase, p, k * 128 + cq * 8) =                             \
                make_uint2(cvtpk(s0, s1), cvtpk(s2, s3));                             \
        }

        // strip 0: meta/wts read from LDS (rows 0..15 writes never clobber tail)
        {
            uint4 q0[9], q1[9];
#pragma unroll
            for (int k = 0; k < 9; ++k) {
                int2 mm = u.A.metaB[p0 * 9 + k];
                q0[k] = gld4(xbB + mm.x);
                q1[k] = gld4(xbB + mm.y);
            }
            asm volatile("s_waitcnt vmcnt(0)" ::: "memory");
            __builtin_amdgcn_sched_barrier(0);
#pragma unroll
            for (int k = 0; k < 9; ++k) {
                uint4 qa = q0[k], qb = q1[k];
                uint2 wh = u.A.wtsH[p0 * 9 + k];
                PACK1(p0, qa, qb, wh.x, wh.y)
            }
        }
        __syncthreads();   // all strip-0 tail reads done before strip-1 clobbers

        // strip 1: snapshot tail to regs, fence, then load/pack
        {
            int p1 = p0 + 16;
            int2 mreg[9];
            uint2 wreg[9];
#pragma unroll
            for (int k = 0; k < 9; ++k) {
                mreg[k] = u.A.metaB[p1 * 9 + k];
                wreg[k] = u.A.wtsH[p1 * 9 + k];
            }
            __syncthreads();   // snapshots complete before any strip-1 smp write
            uint4 q0[9], q1[9];
#pragma unroll
            for (int k = 0; k < 9; ++k) {
                q0[k] = gld4(xbB + mreg[k].x);
                q1[k] = gld4(xbB + mreg[k].y);
            }
            asm volatile("s_waitcnt vmcnt(0)" ::: "memory");
            __builtin_amdgcn_sched_barrier(0);
#pragma unroll
            for (int k = 0; k < 9; ++k) {
                uint4 qa = q0[k], qb = q1[k];
                PACK1(p1, qa, qb, wreg[k].x, wreg[k].y)
            }
        }
#undef PACK1
    }
    __syncthreads();

    // ---- Phase B1: deform MFMA; both strips share wbf fragments ----
    {
        char* smpBase = (char*)u.smp;
        floatx4 acc0 = {0.f, 0.f, 0.f, 0.f};
        floatx4 acc1 = {0.f, 0.f, 0.f, 0.f};
        const short8* ap = (const short8*)(wbf + (size_t)(wv * 16 + r16) * CK + g * 8);
#pragma unroll
        for (int kk = 0; kk < 18; ++kk) {
            short8 a = ap[kk * 4];
            short8 v0 = *(const short8*)smpp(smpBase, r16, g * 16 + kk * 64);
            short8 v1 = *(const short8*)smpp(smpBase, 16 + r16, g * 16 + kk * 64);
            acc0 = __builtin_amdgcn_mfma_f32_16x16x32_bf16(a, v0, acc0, 0, 0, 0);
            acc1 = __builtin_amdgcn_mfma_f32_16x16x32_bf16(a, v1, acc1, 0, 0, 0);
        }
        size_t obase = ((size_t)(b * Cch + wv * 16 + g * 4)) << 14;
        int hw = (h << 7) + w0 + r16;
#pragma unroll
        for (int r = 0; r < 4; ++r) {
            out[obase + ((size_t)r << 14) + hw] = acc0[r];
            out[obase + ((size_t)r << 14) + hw + 16] = acc1[r];
        }
    }
}

// ---------------------------------------------------------------------------
extern "C" void kernel_launch(void* const* d_in, const int* in_sizes, int n_in,
                              void* d_out, int out_size, void* d_ws, size_t ws_size,
                              hipStream_t stream) {
    const float* x      = (const float*)d_in[0];
    const float* ref    = (const float*)d_in[1];
    const float* wo     = (const float*)d_in[2];
    const float* bias   = (const float*)d_in[3];
    const float* weight = (const float*)d_in[4];
    float* out = (float*)d_out;

    unsigned short* w9  = (unsigned short*)d_ws;                      // 72 KB
    unsigned short* wbf = (unsigned short*)((char*)d_ws + 262144);    // 72 KB
    unsigned* xpair     = (unsigned*)((char*)d_ws + 524288);          // 33.5 MB

    hipLaunchKernelGGL(prep, dim3(800), dim3(256), 0, stream,
                       x, ref, wo, weight, xpair, w9, wbf);
    hipLaunchKernelGGL(fused_align, dim3(2048), dim3(256), 0, stream,
                       xpair, w9, wbf, bias, out);
}